// Round 7
// baseline (1074.759 us; speedup 1.0000x reference)
//
#include <hip/hip_runtime.h>
#include <math.h>

// Problem constants (reference: S,B,I,H = 1024,512,5,32; G=4H=128)
#define S_LEN  1024
#define BATCH  512
#define HID    32
#define RING_D 8   // ring depth (steps of producer/consumer slack)

__device__ __forceinline__ float fast_rcp(float x) { return __builtin_amdgcn_rcpf(x); }

__device__ __forceinline__ float sigmoid_f(float x) {
    return fast_rcp(1.0f + __expf(-x));
}

__device__ __forceinline__ float tanh_f(float x) {
    // overflow-safe: t = e^{-2|x|} in (0,1]; tanh = sign(x)*(1-t)/(1+t)
    float t = __expf(-2.0f * fabsf(x));
    float r = (1.0f - t) * fast_rcp(1.0f + t);
    return copysignf(r, x);
}

// broadcast lane k's float to all lanes through an SGPR (VALU only, no LDS)
__device__ __forceinline__ float rl(float v, int k) {
    return __int_as_float(__builtin_amdgcn_readlane(__float_as_int(v), k));
}

// Fused 3-layer LSTM + collapsed linear head. Block = 192 threads = 3 waves;
// wave w = layer w. Each block now owns TWO batch elements (2b, 2b+1): chain A
// and chain B run interleaved in every wave, sharing the weight registers —
// chain B's independent instructions fill chain A's dependency stalls (the
// R3-R6 finding: per-wave stall ~1600 cyc/step is fillable, SIMDs are starved).
// Nonlinearity dedup: after a 2-shfl gate exchange, lanes 0-31 update element
// A's cell and lanes 32-63 element B's (no redundant-half compute).
// Layer handoff: RING_D-deep LDS ring + per-slot sequence flags (R6 scheme).
// Head: y = relu((w3 W2 W1).h2 + (w3 W2 b1 + w3 b2 + b3)) folded into wave 2;
// one 5-shfl butterfly reduces both elements (A in lanes 0-31, B in 32-63).
// Lane l owns gate rows l and l+64 (order i,f,g,o) for BOTH elements.
__global__ __launch_bounds__(192, 1)
void lstm3_x2(const float* __restrict__ x,
              const float* __restrict__ Wih0, const float* __restrict__ Whh0,
              const float* __restrict__ bih0, const float* __restrict__ bhh0,
              const float* __restrict__ Wih1, const float* __restrict__ Whh1,
              const float* __restrict__ bih1, const float* __restrict__ bhh1,
              const float* __restrict__ Wih2, const float* __restrict__ Whh2,
              const float* __restrict__ bih2, const float* __restrict__ bhh2,
              const float* __restrict__ w1, const float* __restrict__ b1,
              const float* __restrict__ w2, const float* __restrict__ b2,
              const float* __restrict__ w3, const float* __restrict__ b3,
              float* __restrict__ out)
{
    const int blk = blockIdx.x;           // owns batch elements 2*blk, 2*blk+1
    const int w = threadIdx.x >> 6;       // wave id == layer id, 0..2
    const int l = threadIdx.x & 63;
    const int j = l & 31;
    const int half = l >> 5;              // 0: element A duties, 1: element B
    const bool lowHalf = (half == 0);
    const int gA = l;
    const int gB = l + 64;

    __shared__ float xlds[S_LEN * 10];          // [s][elem*5+k], both elements
    __shared__ float ring[2][RING_D][2][HID];   // [producer][slot][elem][unit]
    __shared__ int   flg[2][RING_D];            // == s+1 when slot holds step s
    __shared__ int   prog[2];                   // consumer steps completed

    // ---- one-time staging + sync-state init ----
    {
        // x[s][2blk+e][k] = x[s*2560 + blk*10 + e*5 + k]: 10 contiguous floats/s
        const float* xb = x + (size_t)blk * 10;
        for (int i = threadIdx.x; i < S_LEN * 10; i += 192) {
            int s = i / 10;
            int r = i - 10 * s;
            xlds[i] = xb[(size_t)s * (BATCH * 5) + r];
        }
    }
    if (threadIdx.x < 2 * RING_D) (&flg[0][0])[threadIdx.x] = 0;
    if (threadIdx.x < 2) prog[threadIdx.x] = 0;
    __syncthreads();   // the ONLY barrier

    const float* Wih = (w == 0) ? Wih0 : (w == 1) ? Wih1 : Wih2;
    const float* Whh = (w == 0) ? Whh0 : (w == 1) ? Whh1 : Whh2;
    const float* bih = (w == 0) ? bih0 : (w == 1) ? bih1 : bih2;
    const float* bhh = (w == 0) ? bhh0 : (w == 1) ? bhh1 : bhh2;

    // Weight rows in registers — shared by both chains.
    float whhA[HID], whhB[HID];
#pragma unroll
    for (int k = 0; k < HID; ++k) {
        whhA[k] = Whh[gA * HID + k];
        whhB[k] = Whh[gB * HID + k];
    }
    float wihA[HID], wihB[HID];
    if (w == 0) {
#pragma unroll
        for (int k = 0; k < 5; ++k) {
            wihA[k] = Wih[gA * 5 + k];
            wihB[k] = Wih[gB * 5 + k];
        }
    } else {
#pragma unroll
        for (int k = 0; k < HID; ++k) {
            wihA[k] = Wih[gA * HID + k];
            wihB[k] = Wih[gB * HID + k];
        }
    }
    const float biasA = bih[gA] + bhh[gA];
    const float biasB = bih[gB] + bhh[gB];

    // ---- wave-2 prologue: collapse the linear MLP head ----
    float u_own = 0.0f, beta = 0.0f;
    if (w == 2) {
        float t_own = 0.0f;
#pragma unroll
        for (int k = 0; k < HID; ++k)
            t_own += w3[k] * w2[k * HID + j];
        float uo = 0.0f, bt = 0.0f;
#pragma unroll
        for (int k = 0; k < HID; ++k) {
            float tk = rl(t_own, k);       // t_k lives in lane k (low half)
            uo += tk * w1[k * HID + j];
            bt += tk * b1[k] + w3[k] * b2[k];
        }
        u_own = uo;                        // u(j), same for both elements
        beta = bt + b3[0];
    }

    float c = 0.0f;   // my element's c_j   (A for lanes 0-31, B for 32-63)
    float h = 0.0f;   // my element's h_j   -> h_A in lanes 0-31, h_B in 32-63

    for (int s = 0; s < S_LEN; ++s) {
        const int slot = s & (RING_D - 1);

        // ---- consumer: poll flag, issue all hand-off LDS reads early ----
        float4 hinA[HID / 4], hinB[HID / 4];
        if (w > 0) {
            while (__hip_atomic_load(&flg[w - 1][slot], __ATOMIC_ACQUIRE,
                                     __HIP_MEMORY_SCOPE_WORKGROUP) != s + 1) {}
            const float4* rA = reinterpret_cast<const float4*>(&ring[w - 1][slot][0][0]);
            const float4* rB = reinterpret_cast<const float4*>(&ring[w - 1][slot][1][0]);
#pragma unroll
            for (int k4 = 0; k4 < HID / 4; ++k4) { hinA[k4] = rA[k4]; hinB[k4] = rB[k4]; }
        }

        // ---- Whh . h for BOTH chains (readlane distribution; 2 chains/gate) ----
        float aA0_A = biasA, aA1_A = 0.f, aB0_A = biasB, aB1_A = 0.f;
        float aA0_B = biasA, aA1_B = 0.f, aB0_B = biasB, aB1_B = 0.f;
#pragma unroll
        for (int k = 0; k < HID; k += 2) {
            float hA0 = rl(h, k);      float hA1 = rl(h, k + 1);
            float hB0 = rl(h, k + 32); float hB1 = rl(h, k + 33);
            aA0_A += whhA[k] * hA0;  aA1_A += whhA[k + 1] * hA1;
            aB0_A += whhB[k] * hA0;  aB1_A += whhB[k + 1] * hA1;
            aA0_B += whhA[k] * hB0;  aA1_B += whhA[k + 1] * hB1;
            aB0_B += whhB[k] * hB0;  aB1_B += whhB[k + 1] * hB1;
        }

        // ---- input contribution ----
        if (w == 0) {
            const float* xs = &xlds[s * 10];
            float xA0 = xs[0], xA1 = xs[1], xA2 = xs[2], xA3 = xs[3], xA4 = xs[4];
            float xB0 = xs[5], xB1 = xs[6], xB2 = xs[7], xB3 = xs[8], xB4 = xs[9];
            aA0_A += wihA[0] * xA0 + wihA[2] * xA2 + wihA[4] * xA4;
            aA1_A += wihA[1] * xA1 + wihA[3] * xA3;
            aB0_A += wihB[0] * xA0 + wihB[2] * xA2 + wihB[4] * xA4;
            aB1_A += wihB[1] * xA1 + wihB[3] * xA3;
            aA0_B += wihA[0] * xB0 + wihA[2] * xB2 + wihA[4] * xB4;
            aA1_B += wihA[1] * xB1 + wihA[3] * xB3;
            aB0_B += wihB[0] * xB0 + wihB[2] * xB2 + wihB[4] * xB4;
            aB1_B += wihB[1] * xB1 + wihB[3] * xB3;
        } else {
#pragma unroll
            for (int k4 = 0; k4 < HID / 4; ++k4) {
                float4 hA = hinA[k4], hB = hinB[k4];
                aA0_A += wihA[4*k4+0] * hA.x;  aA1_A += wihA[4*k4+1] * hA.y;
                aA0_A += wihA[4*k4+2] * hA.z;  aA1_A += wihA[4*k4+3] * hA.w;
                aB0_A += wihB[4*k4+0] * hA.x;  aB1_A += wihB[4*k4+1] * hA.y;
                aB0_A += wihB[4*k4+2] * hA.z;  aB1_A += wihB[4*k4+3] * hA.w;
                aA0_B += wihA[4*k4+0] * hB.x;  aA1_B += wihA[4*k4+1] * hB.y;
                aA0_B += wihA[4*k4+2] * hB.z;  aA1_B += wihA[4*k4+3] * hB.w;
                aB0_B += wihB[4*k4+0] * hB.x;  aB1_B += wihB[4*k4+1] * hB.y;
                aB0_B += wihB[4*k4+2] * hB.z;  aB1_B += wihB[4*k4+3] * hB.w;
            }
            // free the slot for the producer (release orders the reads above)
            if (l == 0)
                __hip_atomic_store(&prog[w - 1], s + 1, __ATOMIC_RELEASE,
                                   __HIP_MEMORY_SCOPE_WORKGROUP);
        }
        float accA_A = aA0_A + aA1_A;   // gate l     of element A
        float accB_A = aB0_A + aB1_A;   // gate l+64  of element A
        float accA_B = aA0_B + aA1_B;   // gate l     of element B
        float accB_B = aB0_B + aB1_B;   // gate l+64  of element B

        // ---- gate exchange: low half keeps element A, high half element B ----
        // low lane j has i_A,g_A (own) + needs f_A,o_A (from lane j+32)
        // high lane j+32 has f_B,o_B (own) + needs i_B,g_B (from lane j)
        float v1 = lowHalf ? accA_B : accA_A;   // low sends i_B; high sends f_A
        float r1 = __shfl_xor(v1, 32);          // low recv f_A; high recv i_B
        float v2 = lowHalf ? accB_B : accB_A;   // low sends g_B; high sends o_A
        float r2 = __shfl_xor(v2, 32);          // low recv o_A; high recv g_B
        float gi = lowHalf ? accA_A : r1;
        float gf = lowHalf ? r1 : accA_B;
        float gg = lowHalf ? accB_A : r2;
        float go = lowHalf ? r2 : accB_B;

        gi = sigmoid_f(gi);
        gf = sigmoid_f(gf);
        gg = tanh_f(gg);
        go = sigmoid_f(go);
        c = gf * c + gi * gg;
        h = go * tanh_f(c);   // lane j: h_A(j); lane j+32: h_B(j)

        // ---- handoff / output ----
        if (w < 2) {
            if (s >= RING_D) {
                while (__hip_atomic_load(&prog[w], __ATOMIC_ACQUIRE,
                                         __HIP_MEMORY_SCOPE_WORKGROUP)
                       < s - (RING_D - 1)) {}
            }
            ring[w][slot][half][j] = h;          // addr == l: conflict-free
            if (l == 0)
                __hip_atomic_store(&flg[w][slot], s + 1, __ATOMIC_RELEASE,
                                   __HIP_MEMORY_SCOPE_WORKGROUP);
        } else {
            // head for both elements: butterfly within each 32-lane half
            float prt = u_own * h;
            prt += __shfl_xor(prt, 1);
            prt += __shfl_xor(prt, 2);
            prt += __shfl_xor(prt, 4);
            prt += __shfl_xor(prt, 8);
            prt += __shfl_xor(prt, 16);
            if ((l & 31) == 0)
                out[(size_t)s * BATCH + 2 * blk + half] = fmaxf(prt + beta, 0.0f);
        }
    }
}

extern "C" void kernel_launch(void* const* d_in, const int* in_sizes, int n_in,
                              void* d_out, int out_size, void* d_ws, size_t ws_size,
                              hipStream_t stream)
{
    const float* x    = (const float*)d_in[0];
    const float* Wih0 = (const float*)d_in[1];
    const float* Whh0 = (const float*)d_in[2];
    const float* bih0 = (const float*)d_in[3];
    const float* bhh0 = (const float*)d_in[4];
    const float* Wih1 = (const float*)d_in[5];
    const float* Whh1 = (const float*)d_in[6];
    const float* bih1 = (const float*)d_in[7];
    const float* bhh1 = (const float*)d_in[8];
    const float* Wih2 = (const float*)d_in[9];
    const float* Whh2 = (const float*)d_in[10];
    const float* bih2 = (const float*)d_in[11];
    const float* bhh2 = (const float*)d_in[12];
    const float* w1   = (const float*)d_in[13];
    const float* b1   = (const float*)d_in[14];
    const float* w2   = (const float*)d_in[15];
    const float* b2   = (const float*)d_in[16];
    const float* w3   = (const float*)d_in[17];
    const float* b3   = (const float*)d_in[18];

    lstm3_x2<<<BATCH / 2, 192, 0, stream>>>(x, Wih0, Whh0, bih0, bhh0,
                                            Wih1, Whh1, bih1, bhh1,
                                            Wih2, Whh2, bih2, bhh2,
                                            w1, b1, w2, b2, w3, b3,
                                            (float*)d_out);
}

// Round 8
// 1042.097 us; speedup vs baseline: 1.0313x; 1.0313x over previous
//
#include <hip/hip_runtime.h>
#include <math.h>

// Problem constants (reference: S,B,I,H = 1024,512,5,32; G=4H=128)
#define S_LEN 1024
#define BATCH 512
#define HID   32

typedef float f32x2 __attribute__((ext_vector_type(2)));
typedef float f32x4 __attribute__((ext_vector_type(4)));

__device__ __forceinline__ float fast_rcp(float x) { return __builtin_amdgcn_rcpf(x); }

__device__ __forceinline__ float sigmoid_f(float x) {
    return fast_rcp(1.0f + __expf(-x));
}

__device__ __forceinline__ float tanh_f(float x) {
    // overflow-safe: t = e^{-2|x|} in (0,1]; tanh = sign(x)*(1-t)/(1+t)
    float t = __expf(-2.0f * fabsf(x));
    float r = (1.0f - t) * fast_rcp(1.0f + t);
    return copysignf(r, x);
}

// broadcast lane k's float to all lanes through an SGPR (one-time prologue use)
__device__ __forceinline__ float rl(float v, int k) {
    return __int_as_float(__builtin_amdgcn_readlane(__float_as_int(v), k));
}

// quad broadcast via DPP quad_perm: every lane receives the value held by
// lane (quad_base + SRC). VALU pipe, ~4-8 cyc — replaces 120-cyc shfl_xor(32).
template <int SRC>
__device__ __forceinline__ float qb(float v) {
    constexpr int ctrl = SRC * 0x55;  // perm[k] = SRC for all k in the quad
    return __int_as_float(__builtin_amdgcn_mov_dpp(__float_as_int(v), ctrl, 0xF, 0xF, false));
}

// Fused 3-layer LSTM + collapsed linear head, quad-DPP lane mapping.
// Grid 512 (1 batch element/block, 2 blocks/CU). Block = 192 thr = 3 waves;
// wave w = layer w, pipelined with skew (wave w does step s = t - w), ONE
// __syncthreads per tick, double-buffered h in LDS.
// Lane mapping: lane l = 4*u + g (u = l>>2 in 0..15, g = l&3 = gate type in
// torch order i,f,g,o). Lane computes gate rows g*32+u and g*32+u+16 (units u
// and u+16). After the dots, the 4 gates of a unit sit in one QUAD -> gathered
// with 8 v_mov_dpp quad_perm (cheap) instead of shfl_xor(32)/readlane blocks
// (measured ~450 cyc, the R4/R5 finding). All lanes compute the nonlinearity
// for their quad's 2 units redundantly (no divergence, no exchange).
// Dots use f32x2 + __builtin_elementwise_fma to form v_pk_fma_f32.
// Head: y = relu((w3 W2 W1).h2 + (w3 W2 b1 + w3 b2 + b3)) folded into wave 2.
__global__ __launch_bounds__(192, 2)
void lstm3_quad(const float* __restrict__ x,
                const float* __restrict__ Wih0, const float* __restrict__ Whh0,
                const float* __restrict__ bih0, const float* __restrict__ bhh0,
                const float* __restrict__ Wih1, const float* __restrict__ Whh1,
                const float* __restrict__ bih1, const float* __restrict__ bhh1,
                const float* __restrict__ Wih2, const float* __restrict__ Whh2,
                const float* __restrict__ bih2, const float* __restrict__ bhh2,
                const float* __restrict__ w1, const float* __restrict__ b1,
                const float* __restrict__ w2, const float* __restrict__ b2,
                const float* __restrict__ w3, const float* __restrict__ b3,
                float* __restrict__ out)
{
    const int b = blockIdx.x;
    const int w = threadIdx.x >> 6;   // wave id == layer id, 0..2
    const int l = threadIdx.x & 63;
    const int g = l & 3;              // gate type (i,f,g,o)
    const int q = l >> 2;             // first unit of this lane's pair, 0..15
    const int r1 = g * HID + q;       // gate row for unit q
    const int r2 = g * HID + q + 16;  // gate row for unit q+16

    __shared__ float xlds[S_LEN * 5];   // x[s][k] for this batch element
    __shared__ float hbuf[2][3][HID];   // [parity][layer][unit]

    // ---- one-time staging ----
    {
        const float* xb = x + (size_t)b * 5;
        for (int i = threadIdx.x; i < S_LEN * 5; i += 192) {
            int s = i / 5, k = i - 5 * s;
            xlds[i] = xb[(size_t)s * (BATCH * 5) + k];
        }
    }
    for (int i = threadIdx.x; i < 2 * 3 * HID; i += 192)
        (&hbuf[0][0][0])[i] = 0.0f;

    const float* Wih = (w == 0) ? Wih0 : (w == 1) ? Wih1 : Wih2;
    const float* Whh = (w == 0) ? Whh0 : (w == 1) ? Whh1 : Whh2;
    const float* bih = (w == 0) ? bih0 : (w == 1) ? bih1 : bih2;
    const float* bhh = (w == 0) ? bhh0 : (w == 1) ? bhh1 : bhh2;

    // Recurrent weight rows (f32x2-packed for v_pk_fma_f32)
    f32x2 wh1[16], wh2[16];
#pragma unroll
    for (int k2 = 0; k2 < 16; ++k2) {
        wh1[k2] = f32x2{Whh[r1 * HID + 2 * k2], Whh[r1 * HID + 2 * k2 + 1]};
        wh2[k2] = f32x2{Whh[r2 * HID + 2 * k2], Whh[r2 * HID + 2 * k2 + 1]};
    }
    // Input weight rows: layer 0 has K=5, layers 1/2 have K=32
    f32x2 wi1[16], wi2[16];
    float wx1[5], wx2[5];
    if (w == 0) {
#pragma unroll
        for (int k = 0; k < 5; ++k) {
            wx1[k] = Wih[r1 * 5 + k];
            wx2[k] = Wih[r2 * 5 + k];
        }
    } else {
#pragma unroll
        for (int k2 = 0; k2 < 16; ++k2) {
            wi1[k2] = f32x2{Wih[r1 * HID + 2 * k2], Wih[r1 * HID + 2 * k2 + 1]};
            wi2[k2] = f32x2{Wih[r2 * HID + 2 * k2], Wih[r2 * HID + 2 * k2 + 1]};
        }
    }
    const float bias1 = bih[r1] + bhh[r1];
    const float bias2 = bih[r2] + bhh[r2];

    // ---- wave-2 prologue: collapse the linear MLP head ----
    float u_q = 0.0f, u_r = 0.0f, beta = 0.0f;
    if (w == 2) {
        const int j = l & 31;          // lanes 0..31 end holding u[j]
        float t_own = 0.0f;
#pragma unroll
        for (int k = 0; k < HID; ++k)
            t_own += w3[k] * w2[k * HID + j];
        float uo = 0.0f, bt = 0.0f;
#pragma unroll
        for (int k = 0; k < HID; ++k) {
            float tk = rl(t_own, k);   // t_k lives in lane k
            uo += tk * w1[k * HID + j];
            bt += tk * b1[k] + w3[k] * b2[k];
        }
        // move u[j] to the quad mapping: this lane needs u[q] and u[q+16]
        u_q = __int_as_float(__builtin_amdgcn_ds_bpermute(q * 4, __float_as_int(uo)));
        u_r = __int_as_float(__builtin_amdgcn_ds_bpermute((q + 16) * 4, __float_as_int(uo)));
        beta = bt + b3[0];
    }

    float c1 = 0.0f, c2 = 0.0f;   // cell state for units q, q+16 (quad-redundant)

    __syncthreads();   // staging + hbuf zero visible

    for (int t = 0; t < S_LEN + 2; ++t) {
        const int s = t - w;
        const bool active = ((unsigned)s < S_LEN);
        const int p = t & 1;

        // ---- LDS reads first (latency overlaps the dots) ----
        f32x4 hv[8];   // own h (32 floats, same-address broadcast)
        const f32x4* hp = reinterpret_cast<const f32x4*>(&hbuf[p][w][0]);
#pragma unroll
        for (int i = 0; i < 8; ++i) hv[i] = hp[i];

        float v1, v2;
        f32x2 a1 = {0.f, 0.f}, a1b = {0.f, 0.f};
        f32x2 a2 = {0.f, 0.f}, a2b = {0.f, 0.f};
        const f32x2* h2p = reinterpret_cast<const f32x2*>(hv);

        if (w == 0) {
            const int sx = active ? s : 0;
            const float* xs = &xlds[sx * 5];
            float x0 = xs[0], x1 = xs[1], x2 = xs[2], x3 = xs[3], x4 = xs[4];
#pragma unroll
            for (int k2 = 0; k2 < 16; k2 += 2) {
                a1  = __builtin_elementwise_fma(wh1[k2],     h2p[k2],     a1);
                a1b = __builtin_elementwise_fma(wh1[k2 + 1], h2p[k2 + 1], a1b);
                a2  = __builtin_elementwise_fma(wh2[k2],     h2p[k2],     a2);
                a2b = __builtin_elementwise_fma(wh2[k2 + 1], h2p[k2 + 1], a2b);
            }
            v1 = bias1 + (a1.x + a1.y) + (a1b.x + a1b.y)
               + wx1[0] * x0 + wx1[1] * x1 + wx1[2] * x2 + wx1[3] * x3 + wx1[4] * x4;
            v2 = bias2 + (a2.x + a2.y) + (a2b.x + a2b.y)
               + wx2[0] * x0 + wx2[1] * x1 + wx2[2] * x2 + wx2[3] * x3 + wx2[4] * x4;
        } else {
            f32x4 iv[8];   // previous layer's h
            const f32x4* ip = reinterpret_cast<const f32x4*>(&hbuf[p][w - 1][0]);
#pragma unroll
            for (int i = 0; i < 8; ++i) iv[i] = ip[i];
            const f32x2* i2p = reinterpret_cast<const f32x2*>(iv);
            f32x2 d1 = {0.f, 0.f}, d1b = {0.f, 0.f};
            f32x2 d2 = {0.f, 0.f}, d2b = {0.f, 0.f};
#pragma unroll
            for (int k2 = 0; k2 < 16; k2 += 2) {
                a1  = __builtin_elementwise_fma(wh1[k2],     h2p[k2],     a1);
                a1b = __builtin_elementwise_fma(wh1[k2 + 1], h2p[k2 + 1], a1b);
                a2  = __builtin_elementwise_fma(wh2[k2],     h2p[k2],     a2);
                a2b = __builtin_elementwise_fma(wh2[k2 + 1], h2p[k2 + 1], a2b);
                d1  = __builtin_elementwise_fma(wi1[k2],     i2p[k2],     d1);
                d1b = __builtin_elementwise_fma(wi1[k2 + 1], i2p[k2 + 1], d1b);
                d2  = __builtin_elementwise_fma(wi2[k2],     i2p[k2],     d2);
                d2b = __builtin_elementwise_fma(wi2[k2 + 1], i2p[k2 + 1], d2b);
            }
            v1 = bias1 + (a1.x + a1.y) + (a1b.x + a1b.y) + (d1.x + d1.y) + (d1b.x + d1b.y);
            v2 = bias2 + (a2.x + a2.y) + (a2b.x + a2b.y) + (d2.x + d2.y) + (d2b.x + d2b.y);
        }

        // ---- quad gather: 4 gates of each unit via DPP (uniform flow here) ----
        float gi1 = qb<0>(v1), gf1 = qb<1>(v1), gg1 = qb<2>(v1), go1 = qb<3>(v1);
        float gi2 = qb<0>(v2), gf2 = qb<1>(v2), gg2 = qb<2>(v2), go2 = qb<3>(v2);

        float c1n = sigmoid_f(gf1) * c1 + sigmoid_f(gi1) * tanh_f(gg1);
        float h1  = sigmoid_f(go1) * tanh_f(c1n);
        float c2n = sigmoid_f(gf2) * c2 + sigmoid_f(gi2) * tanh_f(gg2);
        float h2n = sigmoid_f(go2) * tanh_f(c2n);

        if (active) {
            c1 = c1n;
            c2 = c2n;
            if (g == 0) {   // quad leader publishes the pair's h
                hbuf[p ^ 1][w][q] = h1;
                hbuf[p ^ 1][w][q + 16] = h2n;
            }
            if (w == 2) {
                // fused head: dot(u, h) over 32 units; quad-mates hold equal
                // partials, xor-butterfly 4/8/16/32 sums the 16 quads
                float prt = u_q * h1 + u_r * h2n;
                prt += __shfl_xor(prt, 4);
                prt += __shfl_xor(prt, 8);
                prt += __shfl_xor(prt, 16);
                prt += __shfl_xor(prt, 32);
                if (l == 0) out[(size_t)s * BATCH + b] = fmaxf(prt + beta, 0.0f);
            }
        }
        __syncthreads();   // tick boundary (no global loads in flight)
    }
}

extern "C" void kernel_launch(void* const* d_in, const int* in_sizes, int n_in,
                              void* d_out, int out_size, void* d_ws, size_t ws_size,
                              hipStream_t stream)
{
    const float* x    = (const float*)d_in[0];
    const float* Wih0 = (const float*)d_in[1];
    const float* Whh0 = (const float*)d_in[2];
    const float* bih0 = (const float*)d_in[3];
    const float* bhh0 = (const float*)d_in[4];
    const float* Wih1 = (const float*)d_in[5];
    const float* Whh1 = (const float*)d_in[6];
    const float* bih1 = (const float*)d_in[7];
    const float* bhh1 = (const float*)d_in[8];
    const float* Wih2 = (const float*)d_in[9];
    const float* Whh2 = (const float*)d_in[10];
    const float* bih2 = (const float*)d_in[11];
    const float* bhh2 = (const float*)d_in[12];
    const float* w1   = (const float*)d_in[13];
    const float* b1   = (const float*)d_in[14];
    const float* w2   = (const float*)d_in[15];
    const float* b2   = (const float*)d_in[16];
    const float* w3   = (const float*)d_in[17];
    const float* b3   = (const float*)d_in[18];

    lstm3_quad<<<BATCH, 192, 0, stream>>>(x, Wih0, Whh0, bih0, bhh0,
                                          Wih1, Whh1, bih1, bhh1,
                                          Wih2, Whh2, bih2, bhh2,
                                          w1, b1, w2, b2, w3, b3,
                                          (float*)d_out);
}